// Round 1
// baseline (1395.662 us; speedup 1.0000x reference)
//
#include <hip/hip_runtime.h>
#include <math.h>

// Problem constants (B=1)
#define NRES 768
#define DIMM 384
#define NH   12

#define SCALAR_SCALE 0.14433756729740646f   // (3*16)^-0.5
#define HALF_POINT   0.06804138174397717f   // 0.5 * (3*4*4.5)^-0.5
#define PAIR_SCALE   0.5773502691896258f    // 3^-0.5

// -------------------- K1: projections + to_global --------------------
// grid 192 blocks x 256 thr; each block handles 4 residue rows, all 1008 output cols.
__global__ __launch_bounds__(256) void k1_proj(
    const float* __restrict__ x, const float* __restrict__ rot, const float* __restrict__ trans,
    const float* __restrict__ Wqs, const float* __restrict__ Wks, const float* __restrict__ Wvs,
    const float* __restrict__ Wqp, const float* __restrict__ Wkp, const float* __restrict__ Wvp,
    float* __restrict__ qs, float* __restrict__ ks, float* __restrict__ vs,
    float* __restrict__ qpg, float* __restrict__ kpg, float* __restrict__ vpg)
{
    __shared__ float xp[3][4][144];   // unrotated point projections staging
    const int tid = threadIdx.x;
    const int n0 = blockIdx.x * 4;
    const float* x0 = x + n0 * DIMM;   // wave-uniform rows -> s_load

    for (int cc = tid; cc < 1008; cc += 256) {
        int m, c, wd;
        if (cc < 576) { m = cc / 192; c = cc - m * 192; wd = 192; }
        else { int z = cc - 576; int zm = z / 144; m = 3 + zm; c = z - zm * 144; wd = 144; }
        const float* Wm = (m==0)?Wqs : (m==1)?Wks : (m==2)?Wvs : (m==3)?Wqp : (m==4)?Wkp : Wvp;
        const float* wp = Wm + c;
        float a0=0.f, a1=0.f, a2=0.f, a3=0.f;
        #pragma unroll 4
        for (int k = 0; k < DIMM; ++k) {
            float w = *wp; wp += wd;
            a0 = fmaf(x0[k],        w, a0);
            a1 = fmaf(x0[384 + k],  w, a1);
            a2 = fmaf(x0[768 + k],  w, a2);
            a3 = fmaf(x0[1152 + k], w, a3);
        }
        if (m < 3) {
            float* dst = (m==0)?qs : (m==1)?ks : vs;
            dst[(n0+0)*192 + c] = a0; dst[(n0+1)*192 + c] = a1;
            dst[(n0+2)*192 + c] = a2; dst[(n0+3)*192 + c] = a3;
        } else {
            int mi = m - 3;
            xp[mi][0][c] = a0; xp[mi][1][c] = a1; xp[mi][2][c] = a2; xp[mi][3][c] = a3;
        }
    }
    __syncthreads();
    // rotate + translate the point projections: out[r] = sum_c p[c]*R[r][c] + t[r]
    for (int t = tid; t < 576; t += 256) {
        int mi = t / 192; int rm = t - mi * 192; int r = rm / 48; int pt = rm - r * 48; int c0 = pt * 3;
        float p0 = xp[mi][r][c0+0], p1 = xp[mi][r][c0+1], p2 = xp[mi][r][c0+2];
        int n = n0 + r;
        const float* R = rot + n * 9; const float* T = trans + n * 3;
        float g0 = fmaf(R[0], p0, fmaf(R[1], p1, fmaf(R[2], p2, T[0])));
        float g1 = fmaf(R[3], p0, fmaf(R[4], p1, fmaf(R[5], p2, T[1])));
        float g2 = fmaf(R[6], p0, fmaf(R[7], p1, fmaf(R[8], p2, T[2])));
        float* dst = (mi==0)?qpg : (mi==1)?kpg : vpg;
        dst[n*144 + c0+0] = g0; dst[n*144 + c0+1] = g1; dst[n*144 + c0+2] = g2;
    }
}

// -------------------- K2: fused attention, one block per query row i --------------------
__global__ __launch_bounds__(256) void k2_attn(
    const float* __restrict__ pairwise, const float* __restrict__ rot, const float* __restrict__ trans,
    const float* __restrict__ Wp, const float* __restrict__ bp, const float* __restrict__ ptw,
    const float* __restrict__ qs, const float* __restrict__ ks, const float* __restrict__ vs,
    const float* __restrict__ qpg, const float* __restrict__ kpg, const float* __restrict__ vpg,
    float* __restrict__ attn_g, float* __restrict__ results)
{
    __shared__ float L[12][769];     // raw logits (padded stride vs 32 banks)
    __shared__ float inv_l[12];      // 1/sum(e) per head
    __shared__ float rp_l[144];      // r_point (global frame, minus trans) staging

    const int tid = threadIdx.x;
    const int i = blockIdx.x;
    const float* qsb = qs + i * 192;    // uniform -> scalar loads
    const float* qpb = qpg + i * 144;   // uniform

    float spw[12];
    #pragma unroll
    for (int h = 0; h < 12; ++h) spw[h] = log1pf(__expf(ptw[h]));  // softplus(point_weights)

    // ---- Phase 1: logits ----
    for (int jj = tid; jj < NRES; jj += 256) {
        const float* kr = ks  + jj * 192;
        const float* kp = kpg + jj * 144;
        const float4* pr = (const float4*)(pairwise + ((size_t)i * NRES + jj) * 128);
        float lg[12];
        #pragma unroll
        for (int h = 0; h < 12; ++h) {
            const float4* k4 = (const float4*)(kr + h * 16);
            float4 a0 = k4[0], a1 = k4[1], a2 = k4[2], a3 = k4[3];
            const float* q = qsb + h * 16;
            float s = q[0]*a0.x + q[1]*a0.y + q[2]*a0.z + q[3]*a0.w
                    + q[4]*a1.x + q[5]*a1.y + q[6]*a1.z + q[7]*a1.w
                    + q[8]*a2.x + q[9]*a2.y + q[10]*a2.z + q[11]*a2.w
                    + q[12]*a3.x + q[13]*a3.y + q[14]*a3.z + q[15]*a3.w;
            const float4* kp4 = (const float4*)(kp + h * 12);
            float4 p0 = kp4[0], p1 = kp4[1], p2 = kp4[2];
            const float* qp = qpb + h * 12;
            float d, dist;
            d = qp[0]  - p0.x; dist  = d*d;
            d = qp[1]  - p0.y; dist += d*d;
            d = qp[2]  - p0.z; dist += d*d;
            d = qp[3]  - p0.w; dist += d*d;
            d = qp[4]  - p1.x; dist += d*d;
            d = qp[5]  - p1.y; dist += d*d;
            d = qp[6]  - p1.z; dist += d*d;
            d = qp[7]  - p1.w; dist += d*d;
            d = qp[8]  - p2.x; dist += d*d;
            d = qp[9]  - p2.y; dist += d*d;
            d = qp[10] - p2.z; dist += d*d;
            d = qp[11] - p2.w; dist += d*d;
            lg[h] = SCALAR_SCALE * s - HALF_POINT * spw[h] * dist;
        }
        float pb[12];
        #pragma unroll
        for (int h = 0; h < 12; ++h) pb[h] = bp[h];
        for (int k4 = 0; k4 < 32; ++k4) {      // pair_bias: 128-dot x 12 heads; W via K$ (uniform)
            float4 pv = pr[k4];
            const float* w = Wp + k4 * 48;
            #pragma unroll
            for (int h = 0; h < 12; ++h) {
                pb[h] = fmaf(pv.x, w[h],
                        fmaf(pv.y, w[12 + h],
                        fmaf(pv.z, w[24 + h],
                        fmaf(pv.w, w[36 + h], pb[h]))));
            }
        }
        #pragma unroll
        for (int h = 0; h < 12; ++h) L[h][jj] = lg[h] + PAIR_SCALE * pb[h];
    }
    __syncthreads();

    // ---- softmax (exact; e left unnormalized, 1/sum folded into epilogues) ----
    {
        int w = tid >> 6, l = tid & 63;
        for (int hq = 0; hq < 3; ++hq) {
            int h = w * 3 + hq;
            float v[12]; float m = -3.0e38f;
            #pragma unroll
            for (int s = 0; s < 12; ++s) { v[s] = L[h][l + 64 * s]; m = fmaxf(m, v[s]); }
            #pragma unroll
            for (int o = 32; o > 0; o >>= 1) m = fmaxf(m, __shfl_xor(m, o));
            float sum = 0.f;
            float* ag = attn_g + ((size_t)i * 12 + h) * NRES;
            #pragma unroll
            for (int s = 0; s < 12; ++s) { float e = __expf(v[s] - m); sum += e; ag[l + 64 * s] = e; }
            #pragma unroll
            for (int o = 32; o > 0; o >>= 1) sum += __shfl_xor(sum, o);
            if (l == 0) inv_l[h] = 1.0f / sum;
        }
    }
    __syncthreads();

    const size_t ri = (size_t)i * 1920;

    // ---- P2a: r_pair (thread = (head-half, pair-dim); attn via scalar loads) ----
    {
        int hh = tid >> 7, d = tid & 127; int hb = hh * 6;
        float acc[6] = {0.f,0.f,0.f,0.f,0.f,0.f};
        const float* pcol = pairwise + (size_t)i * NRES * 128 + d;
        const float* eb = attn_g + ((size_t)i * 12 + hb) * NRES;  // uniform per wave
        #pragma unroll 4
        for (int j = 0; j < NRES; ++j) {
            float pwv = pcol[(size_t)j * 128];
            #pragma unroll
            for (int u = 0; u < 6; ++u) acc[u] = fmaf(eb[u * NRES + j], pwv, acc[u]);
        }
        #pragma unroll
        for (int u = 0; u < 6; ++u)
            results[ri + 384 + (size_t)(hb + u) * 128 + d] = acc[u] * inv_l[hb + u];
    }

    // ---- P2b: r_scalar ----
    if (tid < 192) {
        int h = tid >> 4;
        const float* eb = attn_g + ((size_t)i * 12 + h) * NRES;
        const float* vcol = vs + tid;
        float a = 0.f;
        #pragma unroll 4
        for (int j = 0; j < NRES; ++j) a = fmaf(eb[j], vcol[j * 192], a);
        results[ri + tid] = a * inv_l[h];
    }

    // ---- P2c: r_point (global frame), minus translation ----
    if (tid < 144) {
        int h = tid / 12; int pc = tid - h * 12;
        const float* eb = attn_g + ((size_t)i * 12 + h) * NRES;
        const float* vcol = vpg + tid;
        float a = 0.f;
        #pragma unroll 4
        for (int j = 0; j < NRES; ++j) a = fmaf(eb[j], vcol[j * 144], a);
        int coord = pc - (pc / 3) * 3;
        rp_l[tid] = a * inv_l[h] - trans[i * 3 + coord];
    }
    __syncthreads();

    // ---- rotate back (R^T), write f_point + pnorm ----
    if (tid < 48) {
        int h = tid >> 2, d = tid & 3; int c0 = h * 12 + d * 3;
        float p0 = rp_l[c0], p1 = rp_l[c0 + 1], p2 = rp_l[c0 + 2];
        const float* R = rot + i * 9;   // uniform
        float o0 = p0 * R[0] + p1 * R[3] + p2 * R[6];
        float o1 = p0 * R[1] + p1 * R[4] + p2 * R[7];
        float o2 = p0 * R[2] + p1 * R[5] + p2 * R[8];
        results[ri + 192 + c0 + 0] = o0;
        results[ri + 192 + c0 + 1] = o1;
        results[ri + 192 + c0 + 2] = o2;
        results[ri + 336 + h * 4 + d] = sqrtf(o0*o0 + o1*o1 + o2*o2 + 1e-8f);
    }
}

// -------------------- K3: out = results @ W_out + b_out --------------------
// grid 128 x 384 thr; 6 rows per block; A-rows via scalar loads, W_out coalesced (L2-resident).
__global__ __launch_bounds__(384) void k3_out(
    const float* __restrict__ results, const float* __restrict__ Wo, const float* __restrict__ bo,
    float* __restrict__ out)
{
    const int c = threadIdx.x;
    const int r0 = blockIdx.x * 6;
    const float* A = results + (size_t)r0 * 1920;   // uniform
    const float* wc = Wo + c;
    float a0=0.f,a1=0.f,a2=0.f,a3=0.f,a4=0.f,a5=0.f;
    #pragma unroll 4
    for (int k = 0; k < 1920; ++k) {
        float w = wc[(size_t)k * 384];
        a0 = fmaf(A[k],          w, a0);
        a1 = fmaf(A[1920  + k],  w, a1);
        a2 = fmaf(A[3840  + k],  w, a2);
        a3 = fmaf(A[5760  + k],  w, a3);
        a4 = fmaf(A[7680  + k],  w, a4);
        a5 = fmaf(A[9600  + k],  w, a5);
    }
    float b = bo[c];
    out[(r0+0)*384 + c] = a0 + b;
    out[(r0+1)*384 + c] = a1 + b;
    out[(r0+2)*384 + c] = a2 + b;
    out[(r0+3)*384 + c] = a3 + b;
    out[(r0+4)*384 + c] = a4 + b;
    out[(r0+5)*384 + c] = a5 + b;
}

extern "C" void kernel_launch(void* const* d_in, const int* in_sizes, int n_in,
                              void* d_out, int out_size, void* d_ws, size_t ws_size,
                              hipStream_t stream) {
    const float* x        = (const float*)d_in[0];
    const float* pairwise = (const float*)d_in[1];
    const float* rot      = (const float*)d_in[2];
    const float* trans    = (const float*)d_in[3];
    // d_in[4] = mask: all-true in this problem; unused.
    const float* Wqs   = (const float*)d_in[5];
    const float* Wks   = (const float*)d_in[6];
    const float* Wvs   = (const float*)d_in[7];
    const float* Wqp   = (const float*)d_in[8];
    const float* Wkp   = (const float*)d_in[9];
    const float* Wvp   = (const float*)d_in[10];
    const float* Wp    = (const float*)d_in[11];
    const float* bp    = (const float*)d_in[12];
    const float* ptw   = (const float*)d_in[13];
    const float* Wo    = (const float*)d_in[14];
    const float* bo    = (const float*)d_in[15];
    float* out = (float*)d_out;

    float* ws = (float*)d_ws;
    float* qs      = ws;              // 768*192
    float* ksb     = qs   + 147456;   // 768*192
    float* vsb     = ksb  + 147456;   // 768*192
    float* qpg     = vsb  + 147456;   // 768*144
    float* kpg     = qpg  + 110592;
    float* vpg     = kpg  + 110592;
    float* attn_g  = vpg  + 110592;   // 768*12*768
    float* results = attn_g + 7077888; // 768*1920

    hipLaunchKernelGGL(k1_proj, dim3(192), dim3(256), 0, stream,
                       x, rot, trans, Wqs, Wks, Wvs, Wqp, Wkp, Wvp,
                       qs, ksb, vsb, qpg, kpg, vpg);
    hipLaunchKernelGGL(k2_attn, dim3(768), dim3(256), 0, stream,
                       pairwise, rot, trans, Wp, bp, ptw,
                       qs, ksb, vsb, qpg, kpg, vpg, attn_g, results);
    hipLaunchKernelGGL(k3_out, dim3(128), dim3(384), 0, stream,
                       results, Wo, bo, out);
}

// Round 2
// 877.865 us; speedup vs baseline: 1.5898x; 1.5898x over previous
//
#include <hip/hip_runtime.h>
#include <math.h>

// Problem constants (B=1)
#define NRES 768
#define DIMM 384
#define NH   12

#define SCALAR_SCALE 0.14433756729740646f   // (3*16)^-0.5
#define HALF_POINT   0.06804138174397717f   // 0.5 * (3*4*4.5)^-0.5
#define PAIR_SCALE   0.5773502691896258f    // 3^-0.5

// -------------------- K1: projections + to_global --------------------
// grid 192 x 256 thr; block = 4 residue rows. x rows staged in LDS (broadcast
// reads), weights read as float4 (coalesced, L2-resident). 252 active threads,
// each owns 4 consecutive output cols of the 1008 concatenated projections.
__global__ __launch_bounds__(256) void k1_proj(
    const float* __restrict__ x, const float* __restrict__ rot, const float* __restrict__ trans,
    const float* __restrict__ Wqs, const float* __restrict__ Wks, const float* __restrict__ Wvs,
    const float* __restrict__ Wqp, const float* __restrict__ Wkp, const float* __restrict__ Wvp,
    float* __restrict__ qs, float* __restrict__ ks, float* __restrict__ vs,
    float* __restrict__ qpg, float* __restrict__ kpg, float* __restrict__ vpg)
{
    __shared__ float xs[4 * 384];        // 4 x-rows
    __shared__ float xp[3][4][144];      // unrotated point projections

    const int tid = threadIdx.x;
    const int n0 = blockIdx.x * 4;

    // stage x rows (coalesced float4)
    for (int idx = tid; idx < 384; idx += 256) {
        float4 v = ((const float4*)(x + (size_t)n0 * 384))[idx];
        ((float4*)xs)[idx] = v;
    }
    __syncthreads();

    if (tid < 252) {
        const int g = tid;
        int m, c0, wd;
        if (g < 144) { m = g / 48; c0 = (g - m * 48) * 4; wd = 192; }
        else { int z = g - 144; m = 3 + z / 36; c0 = (z - (m - 3) * 36) * 4; wd = 144; }
        const float* Wm = (m==0)?Wqs : (m==1)?Wks : (m==2)?Wvs : (m==3)?Wqp : (m==4)?Wkp : Wvp;
        const float* wp = Wm + c0;
        float acc[4][4] = {};
        #pragma unroll 2
        for (int k = 0; k < DIMM; ++k) {
            float4 w = *(const float4*)wp; wp += wd;
            #pragma unroll
            for (int r = 0; r < 4; ++r) {
                float xv = xs[r * 384 + k];
                acc[r][0] = fmaf(xv, w.x, acc[r][0]);
                acc[r][1] = fmaf(xv, w.y, acc[r][1]);
                acc[r][2] = fmaf(xv, w.z, acc[r][2]);
                acc[r][3] = fmaf(xv, w.w, acc[r][3]);
            }
        }
        if (m < 3) {
            float* dst = (m==0)?qs : (m==1)?ks : vs;
            #pragma unroll
            for (int r = 0; r < 4; ++r) {
                float4 st = make_float4(acc[r][0], acc[r][1], acc[r][2], acc[r][3]);
                *(float4*)(dst + (size_t)(n0 + r) * 192 + c0) = st;
            }
        } else {
            int mi = m - 3;
            #pragma unroll
            for (int r = 0; r < 4; ++r)
                #pragma unroll
                for (int u = 0; u < 4; ++u) xp[mi][r][c0 + u] = acc[r][u];
        }
    }
    __syncthreads();

    // rotate + translate point projections
    for (int t = tid; t < 576; t += 256) {
        int mi = t / 192; int rm = t - mi * 192; int r = rm / 48; int pt = rm - r * 48; int c0 = pt * 3;
        float p0 = xp[mi][r][c0+0], p1 = xp[mi][r][c0+1], p2 = xp[mi][r][c0+2];
        int n = n0 + r;
        const float* R = rot + n * 9; const float* T = trans + n * 3;
        float g0 = fmaf(R[0], p0, fmaf(R[1], p1, fmaf(R[2], p2, T[0])));
        float g1 = fmaf(R[3], p0, fmaf(R[4], p1, fmaf(R[5], p2, T[1])));
        float g2 = fmaf(R[6], p0, fmaf(R[7], p1, fmaf(R[8], p2, T[2])));
        float* dst = (mi==0)?qpg : (mi==1)?kpg : vpg;
        dst[n*144 + c0+0] = g0; dst[n*144 + c0+1] = g1; dst[n*144 + c0+2] = g2;
    }
}

// -------------------- K2: single-pass fused attention (online softmax) -----
// One block (256 thr) per query row i; 12 j-tiles of 64. pairwise is read
// ONCE, coalesced, through an LDS tile (stride 129 -> <=2-way bank aliasing).
// LDS 51.9 KB -> 3 blocks/CU (12 waves/CU).
__global__ __launch_bounds__(256, 3) void k2_attn(
    const float* __restrict__ pairwise, const float* __restrict__ rot, const float* __restrict__ trans,
    const float* __restrict__ Wp, const float* __restrict__ bp, const float* __restrict__ ptw,
    const float* __restrict__ qs, const float* __restrict__ ks, const float* __restrict__ vs,
    const float* __restrict__ qpg, const float* __restrict__ kpg, const float* __restrict__ vpg,
    float* __restrict__ results)
{
    __shared__ float Pt[64 * 129];        // pairwise tile, padded
    __shared__ float PBp[4 * 64 * 13];    // pair-bias partials [hg][j][h], padded 13
    __shared__ float E[64 * 13];          // unnormalized exp tile [j][h]
    __shared__ float Qs[192], Qp[144];
    __shared__ float mL[12], lL[12], aL[12], invL[12], hpL[12], bpL[12];
    __shared__ float rp_l[144];

    const int tid = threadIdx.x;
    const int i = blockIdx.x;
    const size_t ri = (size_t)i * 1920;

    // preload q slices + per-head constants
    if (tid < 48)                    ((float4*)Qs)[tid]      = ((const float4*)(qs  + (size_t)i * 192))[tid];
    if (tid >= 64 && tid < 100)      ((float4*)Qp)[tid - 64] = ((const float4*)(qpg + (size_t)i * 144))[tid - 64];
    if (tid >= 128 && tid < 140) {
        int h = tid - 128;
        hpL[h] = HALF_POINT * log1pf(__expf(ptw[h]));
        bpL[h] = PAIR_SCALE * bp[h];
        mL[h] = -3.0e38f; lL[h] = 0.f;
    }
    __syncthreads();

    const int j  = tid & 63;
    const int hg = tid >> 6;          // wave index == head group (3 heads)
    const int hh = tid >> 7, dpr = tid & 127, hb = hh * 6;   // r_pair mapping

    float accp[6] = {0.f,0.f,0.f,0.f,0.f,0.f};
    float accs = 0.f, accq = 0.f;
    const int hs = tid >> 4;          // r_scalar head (tid<192)
    const int hq = tid / 12;          // r_point head  (tid<144)

    for (int tile = 0; tile < 12; ++tile) {
        const int j0 = tile * 64;

        // ---- stage pairwise tile (coalesced float4 -> padded LDS) ----
        {
            const float4* Pg = (const float4*)(pairwise + ((size_t)i * NRES + j0) * 128);
            #pragma unroll
            for (int q = 0; q < 8; ++q) {
                int idx = tid + 256 * q;
                float4 v = Pg[idx];
                int row = idx >> 5, c4 = (idx & 31) << 2;
                float* dp = &Pt[row * 129 + c4];
                dp[0] = v.x; dp[1] = v.y; dp[2] = v.z; dp[3] = v.w;
            }
        }
        __syncthreads();

        // ---- Phase B: pair-bias partials (d-quarter, all 12 heads) + own qk/pt ----
        {
            float pbp[12];
            #pragma unroll
            for (int h = 0; h < 12; ++h) pbp[h] = 0.f;
            const int d0 = hg * 32;
            #pragma unroll 4
            for (int d = 0; d < 32; ++d) {
                float p = Pt[j * 129 + d0 + d];
                const float* w = Wp + (d0 + d) * 12;   // wave-uniform -> s_load
                #pragma unroll
                for (int h = 0; h < 12; ++h) pbp[h] = fmaf(p, w[h], pbp[h]);
            }
            const int jg = j0 + j;
            const float* kr = ks  + (size_t)jg * 192;
            const float* kp = kpg + (size_t)jg * 144;
            float own[3];
            #pragma unroll
            for (int e = 0; e < 3; ++e) {
                int h = 3 * hg + e;
                const float4* kv = (const float4*)(kr + h * 16);
                float4 a0 = kv[0], a1 = kv[1], a2 = kv[2], a3 = kv[3];
                const float4* qv = (const float4*)(Qs + h * 16);
                float4 q0 = qv[0], q1 = qv[1], q2 = qv[2], q3 = qv[3];
                float s = q0.x*a0.x + q0.y*a0.y + q0.z*a0.z + q0.w*a0.w
                        + q1.x*a1.x + q1.y*a1.y + q1.z*a1.z + q1.w*a1.w
                        + q2.x*a2.x + q2.y*a2.y + q2.z*a2.z + q2.w*a2.w
                        + q3.x*a3.x + q3.y*a3.y + q3.z*a3.z + q3.w*a3.w;
                const float4* pv = (const float4*)(kp + h * 12);
                float4 p0 = pv[0], p1 = pv[1], p2 = pv[2];
                const float4* qpv = (const float4*)(Qp + h * 12);
                float4 u0 = qpv[0], u1 = qpv[1], u2 = qpv[2];
                float d0v, dist;
                d0v = u0.x - p0.x; dist  = d0v*d0v;
                d0v = u0.y - p0.y; dist += d0v*d0v;
                d0v = u0.z - p0.z; dist += d0v*d0v;
                d0v = u0.w - p0.w; dist += d0v*d0v;
                d0v = u1.x - p1.x; dist += d0v*d0v;
                d0v = u1.y - p1.y; dist += d0v*d0v;
                d0v = u1.z - p1.z; dist += d0v*d0v;
                d0v = u1.w - p1.w; dist += d0v*d0v;
                d0v = u2.x - p2.x; dist += d0v*d0v;
                d0v = u2.y - p2.y; dist += d0v*d0v;
                d0v = u2.z - p2.z; dist += d0v*d0v;
                d0v = u2.w - p2.w; dist += d0v*d0v;
                own[e] = SCALAR_SCALE * s - hpL[h] * dist + bpL[h];
            }
            float* pbw = &PBp[hg * 832 + j * 13];
            #pragma unroll
            for (int h = 0; h < 12; ++h) {
                float v = PAIR_SCALE * pbp[h];
                if (h >= 3 * hg && h < 3 * hg + 3) v += own[h - 3 * hg];
                pbw[h] = v;
            }
        }
        __syncthreads();

        // ---- Phase C: assemble logits, online-softmax update, write E ----
        {
            const float* pbr = &PBp[j * 13];
            float Lv[3], tm[3];
            #pragma unroll
            for (int e = 0; e < 3; ++e) {
                int h = 3 * hg + e;
                Lv[e] = pbr[h] + pbr[832 + h] + pbr[1664 + h] + pbr[2496 + h];
                tm[e] = Lv[e];
            }
            #pragma unroll
            for (int o = 32; o > 0; o >>= 1) {
                #pragma unroll
                for (int e = 0; e < 3; ++e) tm[e] = fmaxf(tm[e], __shfl_xor(tm[e], o));
            }
            float ss[3], mnv[3], alv[3];
            #pragma unroll
            for (int e = 0; e < 3; ++e) {
                int h = 3 * hg + e;
                float mo = mL[h];
                float mn = fmaxf(mo, tm[e]);
                alv[e] = __expf(mo - mn);
                mnv[e] = mn;
                float ev = __expf(Lv[e] - mn);
                E[j * 13 + h] = ev;
                ss[e] = ev;
            }
            #pragma unroll
            for (int o = 32; o > 0; o >>= 1) {
                #pragma unroll
                for (int e = 0; e < 3; ++e) ss[e] += __shfl_xor(ss[e], o);
            }
            if (j == 0) {
                #pragma unroll
                for (int e = 0; e < 3; ++e) {
                    int h = 3 * hg + e;
                    mL[h] = mnv[e]; aL[h] = alv[e];
                    lL[h] = lL[h] * alv[e] + ss[e];
                }
            }
        }
        __syncthreads();

        // ---- Phase D: rescale + accumulate outputs ----
        {   // r_pair: all 256 threads (2 d-halves x 6 heads)
            #pragma unroll
            for (int u = 0; u < 6; ++u) accp[u] *= aL[hb + u];
            #pragma unroll 4
            for (int jj = 0; jj < 64; ++jj) {
                float p = Pt[jj * 129 + dpr];
                const float* ej = &E[jj * 13 + hb];   // lane-uniform -> broadcast
                accp[0] = fmaf(ej[0], p, accp[0]);
                accp[1] = fmaf(ej[1], p, accp[1]);
                accp[2] = fmaf(ej[2], p, accp[2]);
                accp[3] = fmaf(ej[3], p, accp[3]);
                accp[4] = fmaf(ej[4], p, accp[4]);
                accp[5] = fmaf(ej[5], p, accp[5]);
            }
        }
        if (tid < 192) {   // r_scalar
            accs *= aL[hs];
            const float* vb = vs + (size_t)j0 * 192 + tid;
            #pragma unroll 4
            for (int jj = 0; jj < 64; ++jj)
                accs = fmaf(E[jj * 13 + hs], vb[(size_t)jj * 192], accs);
        }
        if (tid < 144) {   // r_point (global frame)
            accq *= aL[hq];
            const float* vb = vpg + (size_t)j0 * 144 + tid;
            #pragma unroll 4
            for (int jj = 0; jj < 64; ++jj)
                accq = fmaf(E[jj * 13 + hq], vb[(size_t)jj * 144], accq);
        }
        __syncthreads();   // protect Pt/E before next tile's staging
    }

    // ---- epilogue ----
    if (tid < 12) invL[tid] = 1.0f / lL[tid];
    __syncthreads();

    #pragma unroll
    for (int u = 0; u < 6; ++u)
        results[ri + 384 + (size_t)(hb + u) * 128 + dpr] = accp[u] * invL[hb + u];

    if (tid < 192) results[ri + tid] = accs * invL[hs];

    if (tid < 144) {
        int pc = tid - hq * 12;
        int coord = pc - (pc / 3) * 3;
        rp_l[tid] = accq * invL[hq] - trans[i * 3 + coord];
    }
    __syncthreads();

    if (tid < 48) {
        int h = tid >> 2, d = tid & 3; int c0 = h * 12 + d * 3;
        float p0 = rp_l[c0], p1 = rp_l[c0 + 1], p2 = rp_l[c0 + 2];
        const float* R = rot + i * 9;
        float o0 = p0 * R[0] + p1 * R[3] + p2 * R[6];
        float o1 = p0 * R[1] + p1 * R[4] + p2 * R[7];
        float o2 = p0 * R[2] + p1 * R[5] + p2 * R[8];
        results[ri + 192 + c0 + 0] = o0;
        results[ri + 192 + c0 + 1] = o1;
        results[ri + 192 + c0 + 2] = o2;
        results[ri + 336 + h * 4 + d] = sqrtf(o0*o0 + o1*o1 + o2*o2 + 1e-8f);
    }
}

// -------------------- K3: out = results @ W_out + b_out --------------------
// grid 192 x 384 thr; 4 rows/block staged in LDS; Wo read as float4 coalesced;
// 4-way k-split with LDS reduction.
__global__ __launch_bounds__(384) void k3_out(
    const float* __restrict__ results, const float* __restrict__ Wo, const float* __restrict__ bo,
    float* __restrict__ out)
{
    __shared__ float As[4 * 1924];
    __shared__ float red[3 * 96 * 17];

    const int t = threadIdx.x;
    const int r0 = blockIdx.x * 4;

    #pragma unroll
    for (int q = 0; q < 5; ++q) {
        int idx = t + 384 * q;
        if (idx < 1920) {
            int r = idx / 480, c4 = idx - r * 480;
            float4 v = ((const float4*)(results + (size_t)(r0 + r) * 1920))[c4];
            float* dp = &As[r * 1924 + c4 * 4];
            dp[0] = v.x; dp[1] = v.y; dp[2] = v.z; dp[3] = v.w;
        }
    }
    __syncthreads();

    const int cg = t % 96, kp = t / 96;
    float acc[4][4] = {};
    const float* wp = Wo + (size_t)(kp * 480) * 384 + cg * 4;
    int ka = kp * 480;
    #pragma unroll 2
    for (int k = 0; k < 480; ++k, ++ka) {
        float4 w = *(const float4*)wp; wp += 384;
        #pragma unroll
        for (int r = 0; r < 4; ++r) {
            float a = As[r * 1924 + ka];   // broadcast
            acc[r][0] = fmaf(a, w.x, acc[r][0]);
            acc[r][1] = fmaf(a, w.y, acc[r][1]);
            acc[r][2] = fmaf(a, w.z, acc[r][2]);
            acc[r][3] = fmaf(a, w.w, acc[r][3]);
        }
    }
    if (kp > 0) {
        float* rp = &red[((kp - 1) * 96 + cg) * 17];
        #pragma unroll
        for (int r = 0; r < 4; ++r)
            #pragma unroll
            for (int u = 0; u < 4; ++u) rp[r * 4 + u] = acc[r][u];
    }
    __syncthreads();
    if (kp == 0) {
        float4 b = *(const float4*)(bo + cg * 4);
        #pragma unroll
        for (int r = 0; r < 4; ++r) {
            const float* r1 = &red[(0 * 96 + cg) * 17 + r * 4];
            const float* r2 = &red[(1 * 96 + cg) * 17 + r * 4];
            const float* r3 = &red[(2 * 96 + cg) * 17 + r * 4];
            float4 o;
            o.x = acc[r][0] + r1[0] + r2[0] + r3[0] + b.x;
            o.y = acc[r][1] + r1[1] + r2[1] + r3[1] + b.y;
            o.z = acc[r][2] + r1[2] + r2[2] + r3[2] + b.z;
            o.w = acc[r][3] + r1[3] + r2[3] + r3[3] + b.w;
            *(float4*)(out + (size_t)(r0 + r) * 384 + cg * 4) = o;
        }
    }
}

extern "C" void kernel_launch(void* const* d_in, const int* in_sizes, int n_in,
                              void* d_out, int out_size, void* d_ws, size_t ws_size,
                              hipStream_t stream) {
    const float* x        = (const float*)d_in[0];
    const float* pairwise = (const float*)d_in[1];
    const float* rot      = (const float*)d_in[2];
    const float* trans    = (const float*)d_in[3];
    // d_in[4] = mask: all-true in this problem; unused.
    const float* Wqs   = (const float*)d_in[5];
    const float* Wks   = (const float*)d_in[6];
    const float* Wvs   = (const float*)d_in[7];
    const float* Wqp   = (const float*)d_in[8];
    const float* Wkp   = (const float*)d_in[9];
    const float* Wvp   = (const float*)d_in[10];
    const float* Wp    = (const float*)d_in[11];
    const float* bp    = (const float*)d_in[12];
    const float* ptw   = (const float*)d_in[13];
    const float* Wo    = (const float*)d_in[14];
    const float* bo    = (const float*)d_in[15];
    float* out = (float*)d_out;

    float* ws = (float*)d_ws;
    float* qs      = ws;              // 768*192
    float* ksb     = qs   + 147456;
    float* vsb     = ksb  + 147456;
    float* qpg     = vsb  + 147456;   // 768*144
    float* kpg     = qpg  + 110592;
    float* vpg     = kpg  + 110592;
    float* results = vpg  + 110592;   // 768*1920

    hipLaunchKernelGGL(k1_proj, dim3(192), dim3(256), 0, stream,
                       x, rot, trans, Wqs, Wks, Wvs, Wqp, Wkp, Wvp,
                       qs, ksb, vsb, qpg, kpg, vpg);
    hipLaunchKernelGGL(k2_attn, dim3(768), dim3(256), 0, stream,
                       pairwise, rot, trans, Wp, bp, ptw,
                       qs, ksb, vsb, qpg, kpg, vpg, results);
    hipLaunchKernelGGL(k3_out, dim3(192), dim3(384), 0, stream,
                       results, Wo, bo, out);
}